// Round 10
// baseline (69.592 us; speedup 1.0000x reference)
//
#include <hip/hip_runtime.h>
#include <hip/hip_bf16.h>
#include <math.h>

// Problem constants (from reference)
#define R_CHK   144
#define N_VAR   576
#define BATCH   512
#define ITERS   3
#define NLEV    16
#define ROW_DEG 15
#define N_EDGE  (R_CHK * ROW_DEG)    // 2160
#define NWORDS  9                    // 576 / 64
#define DEG_PAD 16                   // padded max column degree
#define SENT    0x0F1E2D3C           // index-ready sentinel (!= 0xAAAAAAAA poison)

// ---------------------------------------------------------------------------
// Single dispatch: 512 blocks, one batch each. Block 0 also builds the sparse
// index into ws and release-publishes a flag; other blocks acquire-spin on it
// (all 512 blocks are co-resident: launch_bounds(256,2) => >=2 blocks/CU).
// Decode body is byte-identical to the validated round-9 kernel.
// ---------------------------------------------------------------------------
__launch_bounds__(256, 2)
__global__ void fused_all(const float* __restrict__ r,
                          const float* __restrict__ alpha,
                          const float* __restrict__ beta,
                          const float* __restrict__ eta,
                          const float* __restrict__ qkg,
                          const float* __restrict__ H,
                          int* __restrict__ edge_cols,            // ws: 2160 ints
                          unsigned short* __restrict__ col_pack,  // ws: 576*16 u16
                          int* __restrict__ flag,                 // ws: 1 int
                          float* __restrict__ out) {
    __shared__ union SU {
        struct { unsigned long long sb[R_CHK * NWORDS];          // 10368 B
                 int spref[R_CHK * NWORDS]; } bld;               //  5184 B
        struct { float sE[N_EDGE + 1];                           //  8644 B
                 float st[N_VAR]; } dec;                         //  2304 B
    } u;

    const int b    = blockIdx.x;
    const int t    = threadIdx.x;
    const int w    = t >> 6;
    const int lane = t & 63;

    // Input loads issued early (overlap with build/spin).
    const float rv0 = r[b * N_VAR + t];
    const float rv1 = r[b * N_VAR + t + 256];
    const float rv2 = (t < 64) ? r[b * N_VAR + t + 512] : 0.0f;

    // Quantizer fully in registers: exact searchsorted(side=left) semantics.
    float qk[NLEV], bnd[NLEV - 1];
#pragma unroll
    for (int j = 0; j < NLEV; ++j) qk[j] = qkg[j];
#pragma unroll
    for (int j = 0; j < NLEV - 1; ++j) bnd[j] = 0.5f * (qk[j] + qk[j + 1]);
    auto QZ = [&](float y) -> float {
        float q = qk[0];
#pragma unroll
        for (int j = 0; j < NLEV - 1; ++j) q = (y > bnd[j]) ? qk[j + 1] : q;
        return q;
    };
    const float q0 = QZ(0.0f);

    float av[ITERS], bv[ITERS], ev[ITERS];
#pragma unroll
    for (int i = 0; i < ITERS; ++i) { av[i] = alpha[i]; bv[i] = beta[i]; ev[i] = eta[i]; }

    // ======================= index build / wait ============================
    if (b == 0) {
        // Phase 0: H -> 144x9 u64 bitmask (wave pipelined loads, 27 in flight).
        for (int c0 = 0; c0 < 324; c0 += 27) {
            float h[27];
#pragma unroll
            for (int j = 0; j < 27; ++j) {
                int q = w + 4 * (c0 + j);
                h[j] = H[(q / NWORDS) * N_VAR + (q % NWORDS) * 64 + lane];
            }
#pragma unroll
            for (int j = 0; j < 27; ++j) {
                int q = w + 4 * (c0 + j);
                unsigned long long m = __ballot(h[j] > 0.5f);
                if (lane == 0) u.bld.sb[q] = m;
            }
        }
        __syncthreads();

        // Phase 1: per-row set-bit extraction + word-prefix popcounts.
        if (t < R_CHK) {
            int k = 0, p = 0;
#pragma unroll
            for (int s = 0; s < NWORDS; ++s) {
                unsigned long long m = u.bld.sb[t * NWORDS + s];
                u.bld.spref[t * NWORDS + s] = p;
                p += __popcll(m);
                while (m) {
                    int bpos = __ffsll((long long)m) - 1;
                    if (k < ROW_DEG) edge_cols[t * ROW_DEG + k] = s * 64 + bpos;
                    ++k;
                    m &= m - 1;
                }
            }
        }
        __syncthreads();

        // Phase 2: per-column u16 edge-id tables (ascending row order).
#pragma unroll
        for (int cc = 0; cc < 3; ++cc) {
            const int c = t + 256 * cc;
            if (c < N_VAR) {
                const int wq  = c >> 6;
                const int bit = c & 63;
                const unsigned long long vmask = 1ull << bit;
                const unsigned long long lowm  = vmask - 1ull;
                int n = 0;
                for (int i0 = 0; i0 < R_CHK; i0 += 16) {
                    unsigned long long mw[16];
                    int pf[16];
#pragma unroll
                    for (int j = 0; j < 16; ++j) {
                        mw[j] = u.bld.sb[(i0 + j) * NWORDS + wq];
                        pf[j] = u.bld.spref[(i0 + j) * NWORDS + wq];
                    }
#pragma unroll
                    for (int j = 0; j < 16; ++j) {
                        if (mw[j] & vmask) {
                            int rank = pf[j] + __popcll(mw[j] & lowm);
                            if (n < DEG_PAD)
                                col_pack[c * DEG_PAD + n] =
                                    (unsigned short)((i0 + j) * ROW_DEG + rank);
                            ++n;
                        }
                    }
                }
                for (int j = (n < DEG_PAD ? n : DEG_PAD); j < DEG_PAD; ++j)
                    col_pack[c * DEG_PAD + j] = (unsigned short)N_EDGE;
            }
        }
        __threadfence();                 // make index visible device-wide
        __syncthreads();
        if (t == 0)
            __hip_atomic_store(flag, SENT, __ATOMIC_RELEASE, __HIP_MEMORY_SCOPE_AGENT);
        __syncthreads();                 // union WAR: all done with bld region
    } else {
        if (t == 0) {
            long cnt = 0;
            while (__hip_atomic_load(flag, __ATOMIC_ACQUIRE, __HIP_MEMORY_SCOPE_AGENT)
                   != SENT) {
                __builtin_amdgcn_s_sleep(32);
                if (++cnt > (1L << 26)) break;   // hang guard (never hit)
            }
        }
        __syncthreads();
    }

    // ======================= decode (round-9 body) =========================
    float* sE = u.dec.sE;
    float* st = u.dec.st;

    // u16-packed register column tables (2 ids per u32).
    unsigned pa[8], pb[8], pc[8];
    {
        const uint4* base = (const uint4*)col_pack;
        uint4 a0 = base[t * 2], a1 = base[t * 2 + 1];
        pa[0] = a0.x; pa[1] = a0.y; pa[2] = a0.z; pa[3] = a0.w;
        pa[4] = a1.x; pa[5] = a1.y; pa[6] = a1.z; pa[7] = a1.w;
        uint4 b0 = base[(t + 256) * 2], b1 = base[(t + 256) * 2 + 1];
        pb[0] = b0.x; pb[1] = b0.y; pb[2] = b0.z; pb[3] = b0.w;
        pb[4] = b1.x; pb[5] = b1.y; pb[6] = b1.z; pb[7] = b1.w;
        if (t < 64) {
            uint4 c0 = base[(t + 512) * 2], c1 = base[(t + 512) * 2 + 1];
            pc[0] = c0.x; pc[1] = c0.y; pc[2] = c0.z; pc[3] = c0.w;
            pc[4] = c1.x; pc[5] = c1.y; pc[6] = c1.z; pc[7] = c1.w;
        }
    }

    const bool isrow = (t < R_CHK);
    int cols[ROW_DEG];
    if (isrow) {
#pragma unroll
        for (int k = 0; k < ROW_DEG; ++k) cols[k] = edge_cols[t * ROW_DEG + k];
    }

    st[t] = rv0;
    st[t + 256] = rv1;
    if (t < 64) st[t + 512] = rv2;
    if (t == 0) sE[N_EDGE] = 0.0f;
    __syncthreads();

    float M[ROW_DEG], Eq[ROW_DEG];
    if (isrow) {
#pragma unroll
        for (int k = 0; k < ROW_DEG; ++k) M[k] = st[cols[k]];   // M = H*r
    }

#pragma unroll
    for (int it = 0; it < ITERS; ++it) {
        const float a = av[it], bta = bv[it], et = ev[it];

        if (isrow) {
            if (it > 0) {
                const float etp = ev[it - 1];
#pragma unroll
                for (int k = 0; k < ROW_DEG; ++k) {
                    float x = st[cols[k]] - Eq[k];    // (r+col) - E
                    M[k] = QZ(etp * x);
                }
            }

            float sg[ROW_DEG];
#pragma unroll
            for (int k = 0; k < ROW_DEG; ++k)
                sg[k] = (M[k] > 0.0f) ? 1.0f : ((M[k] < 0.0f) ? -1.0f : 0.0f);
            float t0 = sg[0] * sg[1],  t1 = sg[2] * sg[3];
            float t2 = sg[4] * sg[5],  t3 = sg[6] * sg[7];
            float t4 = sg[8] * sg[9],  t5 = sg[10] * sg[11];
            float t6 = sg[12] * sg[13], t7 = sg[14];
            float u0 = t0 * t1, u1 = t2 * t3, u2 = t4 * t5, u3 = t6 * t7;
            const float prod = (u0 * u1) * (u2 * u3);

            float a1[8], a2[8];
#pragma unroll
            for (int k = 0; k < 7; ++k) {
                float x = fabsf(M[2 * k]), y = fabsf(M[2 * k + 1]);
                a1[k] = fminf(x, y); a2[k] = fmaxf(x, y);
            }
            a1[7] = fabsf(M[14]); a2[7] = INFINITY;
#pragma unroll
            for (int s = 4; s >= 1; s >>= 1) {
#pragma unroll
                for (int k = 0; k < 4; ++k) {
                    if (k < s) {
                        float lo = fminf(a1[k], a1[k + s]);
                        float hi = fminf(fmaxf(a1[k], a1[k + s]), fminf(a2[k], a2[k + s]));
                        a1[k] = lo; a2[k] = hi;
                    }
                }
            }
            const float m1 = a1[0], m2 = a2[0];

            const float ap = a * prod;
            const float g1 = fmaxf(m1 - bta, 0.0f);
            const float g2 = fmaxf(m2 - bta, 0.0f);
            const float y1 = et * (ap * g1);
            const float y2 = et * (ap * g2);
            const float c1p = QZ(y1), c1m = QZ(-y1);
            const float c2p = QZ(y2), c2m = QZ(-y2);
#pragma unroll
            for (int k = 0; k < ROW_DEG; ++k) {
                const bool ismin = (fabsf(M[k]) == m1);    // -> mexcl = m2
                float cp = ismin ? c2p : c1p;
                float cm = ismin ? c2m : c1m;
                float q = (sg[k] > 0.0f) ? cp : cm;
                q = (sg[k] == 0.0f) ? q0 : q;
                Eq[k] = q;
                sE[t * ROW_DEG + k] = q;
            }
        }
        __syncthreads();

        // column phase: fixed-degree sums (ascending row order)
        {
            float s0 = 0.0f, s1 = 0.0f, s2 = 0.0f;
#pragma unroll
            for (int j = 0; j < DEG_PAD; ++j) {
                int id = (pa[j >> 1] >> (16 * (j & 1))) & 0xffff;
                s0 += sE[id];
            }
#pragma unroll
            for (int j = 0; j < DEG_PAD; ++j) {
                int id = (pb[j >> 1] >> (16 * (j & 1))) & 0xffff;
                s1 += sE[id];
            }
            if (t < 64) {
#pragma unroll
                for (int j = 0; j < DEG_PAD; ++j) {
                    int id = (pc[j >> 1] >> (16 * (j & 1))) & 0xffff;
                    s2 += sE[id];
                }
            }
            float w0 = rv0 + s0;
            float w1 = rv1 + s1;
            st[t] = w0;
            st[t + 256] = w1;
            float w2 = 0.0f;
            if (t < 64) { w2 = rv2 + s2; st[t + 512] = w2; }
            if (it == ITERS - 1) {
                out[b * N_VAR + t] = w0;
                out[b * N_VAR + t + 256] = w1;
                if (t < 64) out[b * N_VAR + t + 512] = w2;
            }
        }
        if (it < ITERS - 1) __syncthreads();
    }
}

// ---------------------------------------------------------------------------
extern "C" void kernel_launch(void* const* d_in, const int* in_sizes, int n_in,
                              void* d_out, int out_size, void* d_ws, size_t ws_size,
                              hipStream_t stream) {
    const float* r     = (const float*)d_in[0];
    const float* alpha = (const float*)d_in[1];
    const float* beta  = (const float*)d_in[2];
    const float* eta   = (const float*)d_in[3];
    const float* qk    = (const float*)d_in[4];
    const float* H     = (const float*)d_in[5];
    float* out = (float*)d_out;

    // workspace layout
    int* edge_cols = (int*)d_ws;                                      // 2160 ints
    unsigned short* col_pack = (unsigned short*)(edge_cols + N_EDGE); // 9216 u16
    int* flag = (int*)(col_pack + N_VAR * DEG_PAD);                   // 1 int

    fused_all<<<BATCH, 256, 0, stream>>>(r, alpha, beta, eta, qk, H,
                                         edge_cols, col_pack, flag, out);
}